// Round 11
// baseline (350.137 us; speedup 1.0000x reference)
//
#include <hip/hip_runtime.h>

typedef unsigned short u16;
typedef __bf16 v8bf __attribute__((ext_vector_type(8)));
typedef u16 u16x8 __attribute__((ext_vector_type(8)));
typedef u16 u16x4 __attribute__((ext_vector_type(4)));
typedef float f32x4 __attribute__((ext_vector_type(4)));
typedef unsigned u32x4v __attribute__((ext_vector_type(4)));

#define B_ 4
#define L_ 2048
#define H_ 16
#define D_ 64
#define C_ 1024
#define M_ 8192
#define N1_ 3072
#define K1_ 1024
#define K3_ 3072
#define BH_ 64

// ---------- helpers ----------
__device__ __forceinline__ u16 f2bf(float f) {          // RNE f32 -> bf16
  unsigned u = __builtin_bit_cast(unsigned, f);
  u += 0x7fffu + ((u >> 16) & 1u);
  return (u16)(u >> 16);
}
__device__ __forceinline__ float bf2f(u16 h) {
  unsigned u = ((unsigned)h) << 16;
  return __builtin_bit_cast(float, u);
}
__device__ __forceinline__ f32x4 mfma16(v8bf a, v8bf b, f32x4 c) {
  return __builtin_amdgcn_mfma_f32_16x16x32_bf16(a, b, c, 0, 0, 0);
}
__device__ __forceinline__ void gload_lds16(const void* g, void* l) {
  __builtin_amdgcn_global_load_lds((const __attribute__((address_space(1))) void*)g,
                                   (__attribute__((address_space(3))) void*)l, 16, 0, 0);
}
__device__ __forceinline__ unsigned cvtpk_bf16(float lo, float hi) {
  unsigned r;
  asm("v_cvt_pk_bf16_f32 %0, %1, %2" : "=v"(r) : "v"(lo), "v"(hi));
  return r;
}

// ---------- prep: x -> Xhi bf16 ----------
__global__ __launch_bounds__(256) void k_prep_x(const float* __restrict__ X,
                                                u16* __restrict__ Xhi) {
  size_t i = ((size_t)blockIdx.x * 256 + threadIdx.x) * 4;
  float4 v = *(const float4*)(X + i);
  float f[4] = {v.x, v.y, v.z, v.w};
  u16x4 hi;
#pragma unroll
  for (int j = 0; j < 4; ++j) hi[j] = f2bf(f[j]);
  *(u16x4*)(Xhi + i) = hi;
}

// ---------- prep: w_qkv -> split transposed Ws[n][k3], k3 = [hi | hi | lo] ----------
__global__ __launch_bounds__(256) void k_prep_wqkv(const float* __restrict__ W, u16* __restrict__ Ws) {
  __shared__ float t[64][65];
  int k0 = blockIdx.x * 64;
  int n0 = blockIdx.y * 64;
  int tid = threadIdx.x;
#pragma unroll
  for (int it = 0; it < 16; ++it) {
    int idx = it * 256 + tid;
    int r = idx >> 6, c = idx & 63;
    t[r][c] = W[(size_t)(k0 + r) * N1_ + (n0 + c)];
  }
  __syncthreads();
#pragma unroll
  for (int it = 0; it < 16; ++it) {
    int idx = it * 256 + tid;
    int nr = idx >> 6, kc = idx & 63;
    float f = t[kc][nr];
    u16 hi = f2bf(f);
    u16 lo = f2bf(f - bf2f(hi));
    size_t o = (size_t)(n0 + nr) * K3_ + (size_t)(k0 + kc);
    Ws[o] = hi; Ws[o + 1024] = hi; Ws[o + 2048] = lo;
  }
}

// ---------- prep: w_out -> transposed bf16 Wt[n][k] ----------
__global__ __launch_bounds__(256) void k_prep_wout(const float* __restrict__ W, u16* __restrict__ Wt) {
  __shared__ float t[64][65];
  int k0 = blockIdx.x * 64;
  int n0 = blockIdx.y * 64;
  int tid = threadIdx.x;
#pragma unroll
  for (int it = 0; it < 16; ++it) {
    int idx = it * 256 + tid;
    int r = idx >> 6, c = idx & 63;
    t[r][c] = W[(size_t)(k0 + r) * C_ + (n0 + c)];
  }
  __syncthreads();
#pragma unroll
  for (int it = 0; it < 16; ++it) {
    int idx = it * 256 + tid;
    int nr = idx >> 6, kc = idx & 63;
    Wt[(size_t)(n0 + nr) * K1_ + (k0 + kc)] = f2bf(t[kc][nr]);
  }
}

// ---------- GEMM1: 128x128 tile, BK=64, single-buffered m97 structure, high occupancy ----------
// Q,K = Xhi @ (Whi + Wlo)  [NT=32]; V = Xhi @ Whi [NT=16].
// Q epilogue pre-scales by log2e so attention's exp2 needs no fmaf.
__global__ __launch_bounds__(256) void k_gemm1(const u16* __restrict__ Xhi,
                                               const u16* __restrict__ Ws,
                                               u16* __restrict__ Qh, u16* __restrict__ Ql,
                                               u16* __restrict__ Kh, u16* __restrict__ Vr) {
  __shared__ u16 As[128 * 64];   // 16 KB
  __shared__ u16 Bs[128 * 64];   // 16 KB
  int tid = threadIdx.x;
  int l = tid & 63, w = tid >> 6;          // 4 waves
  int wr = w >> 1, wc = w & 1;             // 2 x 2 wave grid; wave tile 64x64
  int lg = l >> 4, lc = l & 15;

  // XCD swizzle: 1536 % 8 == 0, bijective; mt-major within XCD
  int f = blockIdx.x;
  int lin = (f & 7) * 192 + (f >> 3);
  int mt = lin / 24, nt = lin - mt * 24;   // 64 x 24 tiles
  int m0 = mt * 128, n0 = nt * 128;
  int sreg = nt >> 3;                      // 0=q 1=k 2=v
  int NT = (sreg == 2) ? 16 : 32;

  f32x4 acc[4][4];
#pragma unroll
  for (int mi = 0; mi < 4; ++mi)
#pragma unroll
    for (int ni = 0; ni < 4; ++ni) acc[mi][ni] = (f32x4){0.f, 0.f, 0.f, 0.f};

  for (int t = 0; t < NT; ++t) {
    __syncthreads();                         // all reads of previous tile done
#pragma unroll
    for (int call = 0; call < 4; ++call) {   // A: 128x64 = 16 KB, 4 calls
      int id = call * 256 + tid;
      int row = id >> 3, c = id & 7;
      const u16* src = Xhi + (size_t)(m0 + row) * K1_ + (t & 15) * 64 + ((c ^ (row & 7)) * 8);
      gload_lds16(src, &As[id * 8]);
    }
    int kk = (t < 16) ? t * 64 : 2048 + (t & 15) * 64;   // Whi block, then Wlo block
#pragma unroll
    for (int call = 0; call < 4; ++call) {   // B
      int id = call * 256 + tid;
      int row = id >> 3, c = id & 7;
      const u16* src = Ws + (size_t)(n0 + row) * K3_ + kk + ((c ^ (row & 7)) * 8);
      gload_lds16(src, &Bs[id * 8]);
    }
    __syncthreads();                         // staged data visible
#pragma unroll
    for (int ks = 0; ks < 2; ++ks) {
      v8bf fa[4], fb[4];
#pragma unroll
      for (int mi = 0; mi < 4; ++mi) {
        int row = wr * 64 + mi * 16 + lc;
        fa[mi] = *(const v8bf*)&As[row * 64 + (((ks * 4 + lg) ^ (row & 7)) * 8)];
      }
#pragma unroll
      for (int ni = 0; ni < 4; ++ni) {
        int row = wc * 64 + ni * 16 + lc;
        fb[ni] = *(const v8bf*)&Bs[row * 64 + (((ks * 4 + lg) ^ (row & 7)) * 8)];
      }
      __builtin_amdgcn_s_setprio(1);
#pragma unroll
      for (int mi = 0; mi < 4; ++mi)
#pragma unroll
        for (int ni = 0; ni < 4; ++ni) acc[mi][ni] = mfma16(fa[mi], fb[ni], acc[mi][ni]);
      __builtin_amdgcn_s_setprio(0);
    }
  }

  // ---- epilogue: scatter into per-head split layouts ----
  int h0 = (nt & 7) * 2;
#pragma unroll
  for (int mi = 0; mi < 4; ++mi)
#pragma unroll
    for (int ni = 0; ni < 4; ++ni)
#pragma unroll
      for (int j = 0; j < 4; ++j) {
        int gm = m0 + wr * 64 + mi * 16 + lg * 4 + j;
        int col = wc * 64 + ni * 16 + lc;          // 0..127
        int b_ = gm >> 11, li = gm & 2047;
        int h = h0 + (col >> 6), d = col & 63;
        int bh = b_ * H_ + h;
        float v = acc[mi][ni][j];
        if (sreg == 0) {
          v *= 1.44269504089f;                     // fold log2e into Q
          size_t o = ((size_t)bh * L_ + li) * D_ + d;
          u16 hi = f2bf(v); Qh[o] = hi; Ql[o] = f2bf(v - bf2f(hi));
        } else if (sreg == 1) {
          int row = li & 63;
          size_t o = ((size_t)bh * 32 + (li >> 6)) * 4096 + (size_t)((row * 64 + d) ^ ((row & 7) << 3));
          Kh[o] = f2bf(v);
        } else {
          Vr[((size_t)bh * L_ + li) * D_ + d] = f2bf(v);
        }
      }
}

// ---------- V transpose: Vrow[bh][l][d] -> Vt[bh][d][l] ----------
__global__ __launch_bounds__(256) void k_vt(const u16* __restrict__ Vr, u16* __restrict__ Vt) {
  __shared__ unsigned t[128][65];
  int l0 = blockIdx.x * 128;
  int bh = blockIdx.y;
  int tid = threadIdx.x;
#pragma unroll
  for (int it = 0; it < 32; ++it) {
    int idx = it * 256 + tid;
    int r = idx >> 6, c = idx & 63;
    t[r][c] = Vr[((size_t)bh * L_ + l0 + r) * D_ + c];
  }
  __syncthreads();
#pragma unroll
  for (int it = 0; it < 32; ++it) {
    int idx = it * 256 + tid;
    int d = idx >> 7, lc = idx & 127;
    Vt[((size_t)bh * D_ + d) * L_ + l0 + lc] = (u16)t[lc][d];
  }
}

// ---------- flash attention: KVBLK=128 (2 halves), K LDS dbuf (swizzled), P in registers ----------
// P = exp2(s') with s' = (Q*log2e)·K; the softmax shift is dropped (cancels in o/o_sum).
__global__ __launch_bounds__(256, 3) void k_attn(const u16* __restrict__ Qh, const u16* __restrict__ Ql,
                                                 const u16* __restrict__ Khb,
                                                 const u16* __restrict__ Vt, u16* __restrict__ AO) {
  __shared__ u16 Ks[2][8192];      // [buf][swizzled 128x64 hi]  32 KB total
  int tid = threadIdx.x;
  int l = tid & 63, w = tid >> 6;
  int lg = l >> 4, lc = l & 15;
  int bh = blockIdx.y;
  int wq0 = blockIdx.x * 128 + w * 32;

  v8bf qh[2][2], ql[2][2];
#pragma unroll
  for (int qt = 0; qt < 2; ++qt) {
    size_t qoff = ((size_t)bh * L_ + wq0 + qt * 16 + lc) * D_ + lg * 8;
    qh[qt][0] = *(const v8bf*)(Qh + qoff);
    qh[qt][1] = *(const v8bf*)(Qh + qoff + 32);
    ql[qt][0] = *(const v8bf*)(Ql + qoff);
    ql[qt][1] = *(const v8bf*)(Ql + qoff + 32);
  }

  const u16* KhB = Khb + (size_t)bh * 32 * 4096;
  const u16* VtB = Vt + (size_t)bh * D_ * L_;

  v8bf ones;
#pragma unroll
  for (int j = 0; j < 8; ++j) ones[j] = (__bf16)1.0f;

  f32x4 o[2][4], o_sum[2];
#pragma unroll
  for (int qt = 0; qt < 2; ++qt) {
    o_sum[qt] = (f32x4){0.f, 0.f, 0.f, 0.f};
#pragma unroll
    for (int nb = 0; nb < 4; ++nb) o[qt][nb] = (f32x4){0.f, 0.f, 0.f, 0.f};
  }

#define STAGE(T, BUF)                                                                \
  {                                                                                  \
    size_t kb = (size_t)(T) * 8192;                                                  \
    _Pragma("unroll")                                                                \
    for (int n = 0; n < 4; ++n)                                                      \
      gload_lds16(KhB + kb + (w * 4 + n) * 512 + l * 8, &Ks[BUF][(w * 4 + n) * 512]); \
  }

  STAGE(0, 0);
  for (int t = 0; t < 16; ++t) {
    int buf = t & 1;
    __syncthreads();                       // stage(t) complete & visible
#pragma unroll
    for (int half = 0; half < 2; ++half) {
      // V loads for this half FIRST (so PV's wait can leave stage loads in flight)
      v8bf vf[4][2];
#pragma unroll
      for (int nb = 0; nb < 4; ++nb)
#pragma unroll
        for (int hf = 0; hf < 2; ++hf)
          vf[nb][hf] = *(const v8bf*)(VtB + (size_t)(nb * 16 + lc) * L_ + t * 128 + half * 64 + hf * 32 + lg * 8);
      __builtin_amdgcn_sched_barrier(0);
      if (half == 0 && t < 15) STAGE(t + 1, buf ^ 1);
      __builtin_amdgcn_sched_barrier(0);

      // QK^T per kv-16-block; exp2+pack immediately so s dies per-nb
      unsigned cc[2][4][2];
#pragma unroll
      for (int nb = 0; nb < 4; ++nb) {
        int row = half * 64 + nb * 16 + lc;
        int idx0 = (row * 64 + lg * 8) ^ ((lc & 7) << 3);
        int idx1 = (row * 64 + 32 + lg * 8) ^ ((lc & 7) << 3);
        v8bf kh0 = *(const v8bf*)&Ks[buf][idx0];
        v8bf kh1 = *(const v8bf*)&Ks[buf][idx1];
        f32x4 s0 = {0.f, 0.f, 0.f, 0.f}, s1 = {0.f, 0.f, 0.f, 0.f};
        __builtin_amdgcn_s_setprio(1);
        s0 = mfma16(kh0, qh[0][0], s0); s0 = mfma16(kh1, qh[0][1], s0);
        s0 = mfma16(kh0, ql[0][0], s0); s0 = mfma16(kh1, ql[0][1], s0);
        s1 = mfma16(kh0, qh[1][0], s1); s1 = mfma16(kh1, qh[1][1], s1);
        s1 = mfma16(kh0, ql[1][0], s1); s1 = mfma16(kh1, ql[1][1], s1);
        __builtin_amdgcn_s_setprio(0);
#pragma unroll
        for (int qt = 0; qt < 2; ++qt) {
          f32x4 sv = qt ? s1 : s0;
          float p0 = exp2f(sv[0]);
          float p1 = exp2f(sv[1]);
          float p2 = exp2f(sv[2]);
          float p3 = exp2f(sv[3]);
          cc[qt][nb][0] = cvtpk_bf16(p0, p1);
          cc[qt][nb][1] = cvtpk_bf16(p2, p3);
        }
      }

      // redistribute P into PV A-fragments, all in registers (T12)
      v8bf pf[2][2];
#pragma unroll
      for (int qt = 0; qt < 2; ++qt)
#pragma unroll
        for (int hf = 0; hf < 2; ++hf) {
          unsigned a0 = cc[qt][2 * hf][0], b0 = cc[qt][2 * hf + 1][0];
          unsigned a1 = cc[qt][2 * hf][1], b1 = cc[qt][2 * hf + 1][1];
          asm("v_permlane32_swap_b32 %0, %1" : "+v"(a0), "+v"(b0));
          asm("v_permlane16_swap_b32 %0, %1" : "+v"(a0), "+v"(b0));
          asm("v_permlane32_swap_b32 %0, %1" : "+v"(a1), "+v"(b1));
          asm("v_permlane16_swap_b32 %0, %1" : "+v"(a1), "+v"(b1));
          u32x4v t4 = {a0, a1, b0, b1};
          pf[qt][hf] = __builtin_bit_cast(v8bf, t4);
        }

      __builtin_amdgcn_s_setprio(1);
#pragma unroll
      for (int qt = 0; qt < 2; ++qt) {
#pragma unroll
        for (int nb = 0; nb < 4; ++nb) {
          o[qt][nb] = mfma16(pf[qt][0], vf[nb][0], o[qt][nb]);
          o[qt][nb] = mfma16(pf[qt][1], vf[nb][1], o[qt][nb]);
        }
        o_sum[qt] = mfma16(pf[qt][0], ones, o_sum[qt]);
        o_sum[qt] = mfma16(pf[qt][1], ones, o_sum[qt]);
      }
      __builtin_amdgcn_s_setprio(0);
    }
  }
#undef STAGE

  int b_ = bh >> 4, h = bh & 15;
#pragma unroll
  for (int qt = 0; qt < 2; ++qt)
#pragma unroll
    for (int j = 0; j < 4; ++j) {
      float inv = 1.0f / o_sum[qt][j];
#pragma unroll
      for (int nb = 0; nb < 4; ++nb) {
        int row = wq0 + qt * 16 + lg * 4 + j;
        int cc2 = h * 64 + nb * 16 + lc;
        AO[((size_t)b_ * L_ + row) * C_ + cc2] = f2bf(o[qt][nb][j] * inv);
      }
    }
}

// ---------- GEMM2: out = AO(bf16) @ w_out + b_out, fp32 out ----------
__global__ __launch_bounds__(256) void k_gemm2(const u16* __restrict__ A, const u16* __restrict__ Bt,
                                               const float* __restrict__ bias, float* __restrict__ Out) {
  __shared__ u16 As[128 * 32];
  __shared__ u16 Bs[128 * 32];
  int tid = threadIdx.x;
  int l = tid & 63, w = tid >> 6;
  int wr = w >> 1, wc = w & 1;
  int n0 = blockIdx.x * 128, m0 = blockIdx.y * 128;
  int lg = l >> 4, lc = l & 15;

  f32x4 acc[4][4];
#pragma unroll
  for (int mi = 0; mi < 4; ++mi)
#pragma unroll
    for (int ni = 0; ni < 4; ++ni) acc[mi][ni] = (f32x4){0.f, 0.f, 0.f, 0.f};

  for (int ks = 0; ks < 32; ++ks) {
    __syncthreads();
#pragma unroll
    for (int call = 0; call < 2; ++call) {
      int seg = (call * 4 + w) * 64 + l;
      int row = seg >> 2, off = seg & 3;
      gload_lds16(A + (size_t)(m0 + row) * K1_ + ks * 32 + off * 8, &As[(call * 4 + w) * 512]);
      gload_lds16(Bt + (size_t)(n0 + row) * K1_ + ks * 32 + off * 8, &Bs[(call * 4 + w) * 512]);
    }
    __syncthreads();
    v8bf a[4], b[4];
#pragma unroll
    for (int mi = 0; mi < 4; ++mi) a[mi] = *(const v8bf*)&As[(wr * 64 + mi * 16 + lc) * 32 + lg * 8];
#pragma unroll
    for (int ni = 0; ni < 4; ++ni) b[ni] = *(const v8bf*)&Bs[(wc * 64 + ni * 16 + lc) * 32 + lg * 8];
#pragma unroll
    for (int mi = 0; mi < 4; ++mi)
#pragma unroll
      for (int ni = 0; ni < 4; ++ni) acc[mi][ni] = mfma16(a[mi], b[ni], acc[mi][ni]);
  }

#pragma unroll
  for (int mi = 0; mi < 4; ++mi)
#pragma unroll
    for (int ni = 0; ni < 4; ++ni)
#pragma unroll
      for (int j = 0; j < 4; ++j) {
        int gm = m0 + wr * 64 + mi * 16 + lg * 4 + j;
        int gn = n0 + wc * 64 + ni * 16 + lc;
        Out[(size_t)gm * C_ + gn] = acc[mi][ni][j] + bias[gn];
      }
}

// ---------- launch ----------
extern "C" void kernel_launch(void* const* d_in, const int* in_sizes, int n_in,
                              void* d_out, int out_size, void* d_ws, size_t ws_size,
                              hipStream_t stream) {
  const float* x     = (const float*)d_in[0];
  const float* w_qkv = (const float*)d_in[1];
  const float* w_out = (const float*)d_in[2];
  const float* b_out = (const float*)d_in[3];
  float* out = (float*)d_out;
  char* ws = (char*)d_ws;

  u16* Ws  = (u16*)(ws + 0);            // 18874368
  u16* Qh  = (u16*)(ws + 18874368);
  u16* Ql  = (u16*)(ws + 35651584);
  u16* Kh  = (u16*)(ws + 52428800);     // block-swizzled, hi only
  u16* Vr  = (u16*)(ws + 85983232);
  u16* Vt  = (u16*)(ws + 102760448);
  u16* AO  = (u16*)(ws + 119537664);
  u16* W2t = (u16*)(ws + 136314880);
  u16* Xhi = Vt;   // disjoint lifetime

  k_prep_x<<<dim3(8192), 256, 0, stream>>>(x, Xhi);
  k_prep_wqkv<<<dim3(16, 48), 256, 0, stream>>>(w_qkv, Ws);
  k_prep_wout<<<dim3(16, 16), 256, 0, stream>>>(w_out, W2t);
  k_gemm1<<<dim3(1536), 256, 0, stream>>>(Xhi, Ws, Qh, Ql, Kh, Vr);
  k_vt<<<dim3(16, 64), 256, 0, stream>>>(Vr, Vt);
  k_attn<<<dim3(16, 64), 256, 0, stream>>>(Qh, Ql, Kh, Vt, AO);
  k_gemm2<<<dim3(8, 64), 256, 0, stream>>>(AO, W2t, b_out, out);
}

// Round 12
// 322.170 us; speedup vs baseline: 1.0868x; 1.0868x over previous
//
#include <hip/hip_runtime.h>

typedef unsigned short u16;
typedef __bf16 v8bf __attribute__((ext_vector_type(8)));
typedef u16 u16x8 __attribute__((ext_vector_type(8)));
typedef u16 u16x4 __attribute__((ext_vector_type(4)));
typedef float f32x4 __attribute__((ext_vector_type(4)));
typedef unsigned u32x4v __attribute__((ext_vector_type(4)));

#define B_ 4
#define L_ 2048
#define H_ 16
#define D_ 64
#define C_ 1024
#define M_ 8192
#define N1_ 3072
#define K1_ 1024
#define K3_ 3072
#define BH_ 64

// ---------- helpers ----------
__device__ __forceinline__ u16 f2bf(float f) {          // RNE f32 -> bf16
  unsigned u = __builtin_bit_cast(unsigned, f);
  u += 0x7fffu + ((u >> 16) & 1u);
  return (u16)(u >> 16);
}
__device__ __forceinline__ float bf2f(u16 h) {
  unsigned u = ((unsigned)h) << 16;
  return __builtin_bit_cast(float, u);
}
__device__ __forceinline__ f32x4 mfma16(v8bf a, v8bf b, f32x4 c) {
  return __builtin_amdgcn_mfma_f32_16x16x32_bf16(a, b, c, 0, 0, 0);
}
__device__ __forceinline__ void gload_lds16(const void* g, void* l) {
  __builtin_amdgcn_global_load_lds((const __attribute__((address_space(1))) void*)g,
                                   (__attribute__((address_space(3))) void*)l, 16, 0, 0);
}
__device__ __forceinline__ unsigned cvtpk_bf16(float lo, float hi) {
  unsigned r;
  asm("v_cvt_pk_bf16_f32 %0, %1, %2" : "=v"(r) : "v"(lo), "v"(hi));
  return r;
}

// ---------- prep: x -> Xhi bf16 ----------
__global__ __launch_bounds__(256) void k_prep_x(const float* __restrict__ X,
                                                u16* __restrict__ Xhi) {
  size_t i = ((size_t)blockIdx.x * 256 + threadIdx.x) * 4;
  float4 v = *(const float4*)(X + i);
  float f[4] = {v.x, v.y, v.z, v.w};
  u16x4 hi;
#pragma unroll
  for (int j = 0; j < 4; ++j) hi[j] = f2bf(f[j]);
  *(u16x4*)(Xhi + i) = hi;
}

// ---------- prep: w_qkv -> split transposed Ws[n][k3], k3 = [hi | hi | lo] ----------
__global__ __launch_bounds__(256) void k_prep_wqkv(const float* __restrict__ W, u16* __restrict__ Ws) {
  __shared__ float t[64][65];
  int k0 = blockIdx.x * 64;
  int n0 = blockIdx.y * 64;
  int tid = threadIdx.x;
#pragma unroll
  for (int it = 0; it < 16; ++it) {
    int idx = it * 256 + tid;
    int r = idx >> 6, c = idx & 63;
    t[r][c] = W[(size_t)(k0 + r) * N1_ + (n0 + c)];
  }
  __syncthreads();
#pragma unroll
  for (int it = 0; it < 16; ++it) {
    int idx = it * 256 + tid;
    int nr = idx >> 6, kc = idx & 63;
    float f = t[kc][nr];
    u16 hi = f2bf(f);
    u16 lo = f2bf(f - bf2f(hi));
    size_t o = (size_t)(n0 + nr) * K3_ + (size_t)(k0 + kc);
    Ws[o] = hi; Ws[o + 1024] = hi; Ws[o + 2048] = lo;
  }
}

// ---------- prep: w_out -> transposed bf16 Wt[n][k] ----------
__global__ __launch_bounds__(256) void k_prep_wout(const float* __restrict__ W, u16* __restrict__ Wt) {
  __shared__ float t[64][65];
  int k0 = blockIdx.x * 64;
  int n0 = blockIdx.y * 64;
  int tid = threadIdx.x;
#pragma unroll
  for (int it = 0; it < 16; ++it) {
    int idx = it * 256 + tid;
    int r = idx >> 6, c = idx & 63;
    t[r][c] = W[(size_t)(k0 + r) * C_ + (n0 + c)];
  }
  __syncthreads();
#pragma unroll
  for (int it = 0; it < 16; ++it) {
    int idx = it * 256 + tid;
    int nr = idx >> 6, kc = idx & 63;
    Wt[(size_t)(n0 + nr) * K1_ + (k0 + kc)] = f2bf(t[kc][nr]);
  }
}

// ---------- GEMM1: 128x128 tile, BK=64, single-buffered m97 structure, high occupancy ----------
// Q,K = Xhi @ (Whi + Wlo)  [NT=32]; V = Xhi @ Whi [NT=16].
// Q epilogue pre-scales by log2e so attention's exp2 needs no fmaf.
__global__ __launch_bounds__(256) void k_gemm1(const u16* __restrict__ Xhi,
                                               const u16* __restrict__ Ws,
                                               u16* __restrict__ Qh, u16* __restrict__ Ql,
                                               u16* __restrict__ Kh, u16* __restrict__ Vr) {
  __shared__ u16 As[128 * 64];   // 16 KB
  __shared__ u16 Bs[128 * 64];   // 16 KB
  int tid = threadIdx.x;
  int l = tid & 63, w = tid >> 6;          // 4 waves
  int wr = w >> 1, wc = w & 1;             // 2 x 2 wave grid; wave tile 64x64
  int lg = l >> 4, lc = l & 15;

  // XCD swizzle: 1536 % 8 == 0, bijective; mt-major within XCD
  int f = blockIdx.x;
  int lin = (f & 7) * 192 + (f >> 3);
  int mt = lin / 24, nt = lin - mt * 24;   // 64 x 24 tiles
  int m0 = mt * 128, n0 = nt * 128;
  int sreg = nt >> 3;                      // 0=q 1=k 2=v
  int NT = (sreg == 2) ? 16 : 32;

  f32x4 acc[4][4];
#pragma unroll
  for (int mi = 0; mi < 4; ++mi)
#pragma unroll
    for (int ni = 0; ni < 4; ++ni) acc[mi][ni] = (f32x4){0.f, 0.f, 0.f, 0.f};

  for (int t = 0; t < NT; ++t) {
    __syncthreads();                         // all reads of previous tile done
#pragma unroll
    for (int call = 0; call < 4; ++call) {   // A: 128x64 = 16 KB, 4 calls
      int id = call * 256 + tid;
      int row = id >> 3, c = id & 7;
      const u16* src = Xhi + (size_t)(m0 + row) * K1_ + (t & 15) * 64 + ((c ^ (row & 7)) * 8);
      gload_lds16(src, &As[id * 8]);
    }
    int kk = (t < 16) ? t * 64 : 2048 + (t & 15) * 64;   // Whi block, then Wlo block
#pragma unroll
    for (int call = 0; call < 4; ++call) {   // B
      int id = call * 256 + tid;
      int row = id >> 3, c = id & 7;
      const u16* src = Ws + (size_t)(n0 + row) * K3_ + kk + ((c ^ (row & 7)) * 8);
      gload_lds16(src, &Bs[id * 8]);
    }
    __syncthreads();                         // staged data visible
#pragma unroll
    for (int ks = 0; ks < 2; ++ks) {
      v8bf fa[4], fb[4];
#pragma unroll
      for (int mi = 0; mi < 4; ++mi) {
        int row = wr * 64 + mi * 16 + lc;
        fa[mi] = *(const v8bf*)&As[row * 64 + (((ks * 4 + lg) ^ (row & 7)) * 8)];
      }
#pragma unroll
      for (int ni = 0; ni < 4; ++ni) {
        int row = wc * 64 + ni * 16 + lc;
        fb[ni] = *(const v8bf*)&Bs[row * 64 + (((ks * 4 + lg) ^ (row & 7)) * 8)];
      }
      __builtin_amdgcn_s_setprio(1);
#pragma unroll
      for (int mi = 0; mi < 4; ++mi)
#pragma unroll
        for (int ni = 0; ni < 4; ++ni) acc[mi][ni] = mfma16(fa[mi], fb[ni], acc[mi][ni]);
      __builtin_amdgcn_s_setprio(0);
    }
  }

  // ---- epilogue: scatter into per-head split layouts ----
  int h0 = (nt & 7) * 2;
#pragma unroll
  for (int mi = 0; mi < 4; ++mi)
#pragma unroll
    for (int ni = 0; ni < 4; ++ni)
#pragma unroll
      for (int j = 0; j < 4; ++j) {
        int gm = m0 + wr * 64 + mi * 16 + lg * 4 + j;
        int col = wc * 64 + ni * 16 + lc;          // 0..127
        int b_ = gm >> 11, li = gm & 2047;
        int h = h0 + (col >> 6), d = col & 63;
        int bh = b_ * H_ + h;
        float v = acc[mi][ni][j];
        if (sreg == 0) {
          v *= 1.44269504089f;                     // fold log2e into Q
          size_t o = ((size_t)bh * L_ + li) * D_ + d;
          u16 hi = f2bf(v); Qh[o] = hi; Ql[o] = f2bf(v - bf2f(hi));
        } else if (sreg == 1) {
          int row = li & 63;
          size_t o = ((size_t)bh * 32 + (li >> 6)) * 4096 + (size_t)((row * 64 + d) ^ ((row & 7) << 3));
          Kh[o] = f2bf(v);
        } else {
          Vr[((size_t)bh * L_ + li) * D_ + d] = f2bf(v);
        }
      }
}

// ---------- V transpose: Vrow[bh][l][d] -> Vt[bh][d][l] ----------
__global__ __launch_bounds__(256) void k_vt(const u16* __restrict__ Vr, u16* __restrict__ Vt) {
  __shared__ unsigned t[128][65];
  int l0 = blockIdx.x * 128;
  int bh = blockIdx.y;
  int tid = threadIdx.x;
#pragma unroll
  for (int it = 0; it < 32; ++it) {
    int idx = it * 256 + tid;
    int r = idx >> 6, c = idx & 63;
    t[r][c] = Vr[((size_t)bh * L_ + l0 + r) * D_ + c];
  }
  __syncthreads();
#pragma unroll
  for (int it = 0; it < 32; ++it) {
    int idx = it * 256 + tid;
    int d = idx >> 7, lc = idx & 127;
    Vt[((size_t)bh * D_ + d) * L_ + l0 + lc] = (u16)t[lc][d];
  }
}

// ---------- flash attention: KVBLK=64 (r10 structure), K LDS dbuf (swizzled), P in registers ----------
// P = exp2(s') with s' = (Q*log2e)·K; softmax shift dropped (cancels in o/o_sum).
__global__ __launch_bounds__(256, 3) void k_attn(const u16* __restrict__ Qh, const u16* __restrict__ Ql,
                                                 const u16* __restrict__ Khb,
                                                 const u16* __restrict__ Vt, u16* __restrict__ AO) {
  __shared__ u16 Ks[2][4096];      // 16 KB total
  int tid = threadIdx.x;
  int l = tid & 63, w = tid >> 6;
  int lg = l >> 4, lc = l & 15;
  int bh = blockIdx.y;
  int wq0 = blockIdx.x * 128 + w * 32;

  v8bf qh[2][2], ql[2][2];
#pragma unroll
  for (int qt = 0; qt < 2; ++qt) {
    size_t qoff = ((size_t)bh * L_ + wq0 + qt * 16 + lc) * D_ + lg * 8;
    qh[qt][0] = *(const v8bf*)(Qh + qoff);
    qh[qt][1] = *(const v8bf*)(Qh + qoff + 32);
    ql[qt][0] = *(const v8bf*)(Ql + qoff);
    ql[qt][1] = *(const v8bf*)(Ql + qoff + 32);
  }

  const u16* KhB = Khb + (size_t)bh * 32 * 4096;
  const u16* VtB = Vt + (size_t)bh * D_ * L_;

  v8bf ones;
#pragma unroll
  for (int j = 0; j < 8; ++j) ones[j] = (__bf16)1.0f;

  f32x4 o[2][4], o_sum[2];
#pragma unroll
  for (int qt = 0; qt < 2; ++qt) {
    o_sum[qt] = (f32x4){0.f, 0.f, 0.f, 0.f};
#pragma unroll
    for (int nb = 0; nb < 4; ++nb) o[qt][nb] = (f32x4){0.f, 0.f, 0.f, 0.f};
  }

#define STAGE(T, BUF)                                                                \
  {                                                                                  \
    size_t kb = (size_t)(T) * 4096;                                                  \
    _Pragma("unroll")                                                                \
    for (int n = 0; n < 2; ++n)                                                      \
      gload_lds16(KhB + kb + (w * 2 + n) * 512 + l * 8, &Ks[BUF][(w * 2 + n) * 512]); \
  }

  STAGE(0, 0);
  for (int t = 0; t < 32; ++t) {
    int buf = t & 1;
    __syncthreads();                       // stage(t) complete & visible
    // V loads FIRST, then stage(t+1): PV's vf wait leaves stage loads in flight
    v8bf vf[4][2];
#pragma unroll
    for (int nb = 0; nb < 4; ++nb)
#pragma unroll
      for (int hf = 0; hf < 2; ++hf)
        vf[nb][hf] = *(const v8bf*)(VtB + (size_t)(nb * 16 + lc) * L_ + t * 64 + hf * 32 + lg * 8);
    __builtin_amdgcn_sched_barrier(0);
    if (t < 31) STAGE(t + 1, buf ^ 1);
    __builtin_amdgcn_sched_barrier(0);

    // QK^T per kv-16-block; exp2+pack immediately so s dies per-nb
    unsigned cc[2][4][2];
#pragma unroll
    for (int nb = 0; nb < 4; ++nb) {
      int idx0 = ((nb * 16 + lc) * 64 + lg * 8) ^ ((lc & 7) << 3);
      int idx1 = ((nb * 16 + lc) * 64 + 32 + lg * 8) ^ ((lc & 7) << 3);
      v8bf kh0 = *(const v8bf*)&Ks[buf][idx0];
      v8bf kh1 = *(const v8bf*)&Ks[buf][idx1];
      f32x4 s0 = {0.f, 0.f, 0.f, 0.f}, s1 = {0.f, 0.f, 0.f, 0.f};
      __builtin_amdgcn_s_setprio(1);
      s0 = mfma16(kh0, qh[0][0], s0); s0 = mfma16(kh1, qh[0][1], s0);
      s0 = mfma16(kh0, ql[0][0], s0); s0 = mfma16(kh1, ql[0][1], s0);
      s1 = mfma16(kh0, qh[1][0], s1); s1 = mfma16(kh1, qh[1][1], s1);
      s1 = mfma16(kh0, ql[1][0], s1); s1 = mfma16(kh1, ql[1][1], s1);
      __builtin_amdgcn_s_setprio(0);
#pragma unroll
      for (int qt = 0; qt < 2; ++qt) {
        f32x4 sv = qt ? s1 : s0;
        float p0 = exp2f(sv[0]);
        float p1 = exp2f(sv[1]);
        float p2 = exp2f(sv[2]);
        float p3 = exp2f(sv[3]);
        cc[qt][nb][0] = cvtpk_bf16(p0, p1);
        cc[qt][nb][1] = cvtpk_bf16(p2, p3);
      }
    }

    // redistribute P into PV A-fragments, all in registers (T12)
    v8bf pf[2][2];
#pragma unroll
    for (int qt = 0; qt < 2; ++qt)
#pragma unroll
      for (int hf = 0; hf < 2; ++hf) {
        unsigned a0 = cc[qt][2 * hf][0], b0 = cc[qt][2 * hf + 1][0];
        unsigned a1 = cc[qt][2 * hf][1], b1 = cc[qt][2 * hf + 1][1];
        asm("v_permlane32_swap_b32 %0, %1" : "+v"(a0), "+v"(b0));
        asm("v_permlane16_swap_b32 %0, %1" : "+v"(a0), "+v"(b0));
        asm("v_permlane32_swap_b32 %0, %1" : "+v"(a1), "+v"(b1));
        asm("v_permlane16_swap_b32 %0, %1" : "+v"(a1), "+v"(b1));
        u32x4v t4 = {a0, a1, b0, b1};
        pf[qt][hf] = __builtin_bit_cast(v8bf, t4);
      }

    __builtin_amdgcn_s_setprio(1);
#pragma unroll
    for (int qt = 0; qt < 2; ++qt) {
#pragma unroll
      for (int nb = 0; nb < 4; ++nb) {
        o[qt][nb] = mfma16(pf[qt][0], vf[nb][0], o[qt][nb]);
        o[qt][nb] = mfma16(pf[qt][1], vf[nb][1], o[qt][nb]);
      }
      o_sum[qt] = mfma16(pf[qt][0], ones, o_sum[qt]);
      o_sum[qt] = mfma16(pf[qt][1], ones, o_sum[qt]);
    }
    __builtin_amdgcn_s_setprio(0);
  }
#undef STAGE

  int b_ = bh >> 4, h = bh & 15;
#pragma unroll
  for (int qt = 0; qt < 2; ++qt)
#pragma unroll
    for (int j = 0; j < 4; ++j) {
      float inv = 1.0f / o_sum[qt][j];
#pragma unroll
      for (int nb = 0; nb < 4; ++nb) {
        int row = wq0 + qt * 16 + lg * 4 + j;
        int cc2 = h * 64 + nb * 16 + lc;
        AO[((size_t)b_ * L_ + row) * C_ + cc2] = f2bf(o[qt][nb][j] * inv);
      }
    }
}

// ---------- GEMM2: out = AO(bf16) @ w_out + b_out, fp32 out ----------
__global__ __launch_bounds__(256) void k_gemm2(const u16* __restrict__ A, const u16* __restrict__ Bt,
                                               const float* __restrict__ bias, float* __restrict__ Out) {
  __shared__ u16 As[128 * 32];
  __shared__ u16 Bs[128 * 32];
  int tid = threadIdx.x;
  int l = tid & 63, w = tid >> 6;
  int wr = w >> 1, wc = w & 1;
  int n0 = blockIdx.x * 128, m0 = blockIdx.y * 128;
  int lg = l >> 4, lc = l & 15;

  f32x4 acc[4][4];
#pragma unroll
  for (int mi = 0; mi < 4; ++mi)
#pragma unroll
    for (int ni = 0; ni < 4; ++ni) acc[mi][ni] = (f32x4){0.f, 0.f, 0.f, 0.f};

  for (int ks = 0; ks < 32; ++ks) {
    __syncthreads();
#pragma unroll
    for (int call = 0; call < 2; ++call) {
      int seg = (call * 4 + w) * 64 + l;
      int row = seg >> 2, off = seg & 3;
      gload_lds16(A + (size_t)(m0 + row) * K1_ + ks * 32 + off * 8, &As[(call * 4 + w) * 512]);
      gload_lds16(Bt + (size_t)(n0 + row) * K1_ + ks * 32 + off * 8, &Bs[(call * 4 + w) * 512]);
    }
    __syncthreads();
    v8bf a[4], b[4];
#pragma unroll
    for (int mi = 0; mi < 4; ++mi) a[mi] = *(const v8bf*)&As[(wr * 64 + mi * 16 + lc) * 32 + lg * 8];
#pragma unroll
    for (int ni = 0; ni < 4; ++ni) b[ni] = *(const v8bf*)&Bs[(wc * 64 + ni * 16 + lc) * 32 + lg * 8];
#pragma unroll
    for (int mi = 0; mi < 4; ++mi)
#pragma unroll
      for (int ni = 0; ni < 4; ++ni) acc[mi][ni] = mfma16(a[mi], b[ni], acc[mi][ni]);
  }

#pragma unroll
  for (int mi = 0; mi < 4; ++mi)
#pragma unroll
    for (int ni = 0; ni < 4; ++ni)
#pragma unroll
      for (int j = 0; j < 4; ++j) {
        int gm = m0 + wr * 64 + mi * 16 + lg * 4 + j;
        int gn = n0 + wc * 64 + ni * 16 + lc;
        Out[(size_t)gm * C_ + gn] = acc[mi][ni][j] + bias[gn];
      }
}

// ---------- launch ----------
extern "C" void kernel_launch(void* const* d_in, const int* in_sizes, int n_in,
                              void* d_out, int out_size, void* d_ws, size_t ws_size,
                              hipStream_t stream) {
  const float* x     = (const float*)d_in[0];
  const float* w_qkv = (const float*)d_in[1];
  const float* w_out = (const float*)d_in[2];
  const float* b_out = (const float*)d_in[3];
  float* out = (float*)d_out;
  char* ws = (char*)d_ws;

  u16* Ws  = (u16*)(ws + 0);            // 18874368
  u16* Qh  = (u16*)(ws + 18874368);
  u16* Ql  = (u16*)(ws + 35651584);
  u16* Kh  = (u16*)(ws + 52428800);     // block-swizzled, hi only
  u16* Vr  = (u16*)(ws + 85983232);
  u16* Vt  = (u16*)(ws + 102760448);
  u16* AO  = (u16*)(ws + 119537664);
  u16* W2t = (u16*)(ws + 136314880);
  u16* Xhi = Vt;   // disjoint lifetime

  k_prep_x<<<dim3(8192), 256, 0, stream>>>(x, Xhi);
  k_prep_wqkv<<<dim3(16, 48), 256, 0, stream>>>(w_qkv, Ws);
  k_prep_wout<<<dim3(16, 16), 256, 0, stream>>>(w_out, W2t);
  k_gemm1<<<dim3(1536), 256, 0, stream>>>(Xhi, Ws, Qh, Ql, Kh, Vr);
  k_vt<<<dim3(16, 64), 256, 0, stream>>>(Vr, Vt);
  k_attn<<<dim3(16, 64), 256, 0, stream>>>(Qh, Ql, Kh, Vt, AO);
  k_gemm2<<<dim3(8, 64), 256, 0, stream>>>(AO, W2t, b_out, out);
}